// Round 12
// baseline (225.471 us; speedup 1.0000x reference)
//
#include <hip/hip_runtime.h>
#include <cstdint>

#define BB 32768
#define II 1024
#define HH 1024
#define SPLIT 16
#define KCH (BB/SPLIT)      // 2048
#define NT1_32 (II/32)      // 32 K-tiles of 32 (gemm1)
#define NT2 (KCH/64)        // 32 K-tiles of 64 per split (gemm2)

typedef _Float16 f16;
typedef _Float16 f16x4 __attribute__((ext_vector_type(4)));
typedef _Float16 f16x8 __attribute__((ext_vector_type(8)));
typedef float f32x4 __attribute__((ext_vector_type(4)));

typedef const __attribute__((address_space(1))) void gvoid_t;
typedef __attribute__((address_space(3))) void lvoid_t;

__device__ __forceinline__ void gload16(const void* g, void* l){
    __builtin_amdgcn_global_load_lds((gvoid_t*)g, (lvoid_t*)l, 16, 0, 0);
}

__device__ __forceinline__ float tanh_fast(float s){
    float a = fabsf(s);
    float e = __expf(-2.0f * a);
    float t = __fdividef(1.0f - e, 1.0f + e);
    return s < 0.0f ? -t : t;
}

// Fused prep: blocks [0,512): x [B][I] -> xf f16 + xt f16 [I][B]
//             blocks [512,528): W [I][H] -> wt f16 [H][I]
__global__ __launch_bounds__(256) void k_prep2(const float* __restrict__ x,
                                               f16* __restrict__ xf,
                                               f16* __restrict__ xt,
                                               const float* __restrict__ W,
                                               f16* __restrict__ wt){
    __shared__ float lt[64*67];
    const int t = threadIdx.x;
    const int bx = (int)blockIdx.x;
    const float* in; f16* cvt; f16* tr; int C, R, r0;
    if (bx < 512){ in = x; cvt = xf; tr = xt; C = II; R = BB; r0 = bx*64; }
    else         { in = W; cvt = nullptr; tr = wt; C = HH; R = II; r0 = (bx-512)*64; }
    const int c0 = blockIdx.y*64;
    #pragma unroll
    for (int p=0; p<4; ++p){
        int r = p*16 + (t>>4);
        int c = (t&15)*4;
        f32x4 v = __builtin_nontemporal_load((const f32x4*)&in[(size_t)(r0+r)*C + c0 + c]);
        if (cvt){
            f16x4 hv = {(f16)v[0],(f16)v[1],(f16)v[2],(f16)v[3]};
            *(f16x4*)&cvt[(size_t)(r0+r)*C + c0 + c] = hv;
        }
        lt[r*67 + c+0] = v[0];
        lt[r*67 + c+1] = v[1];
        lt[r*67 + c+2] = v[2];
        lt[r*67 + c+3] = v[3];
    }
    __syncthreads();
    const int c = t>>2, rb = (t&3)*16;
    f16x8 a, b;
    #pragma unroll
    for (int e=0; e<8; ++e) a[e] = (f16)lt[(rb+e)*67 + c];
    #pragma unroll
    for (int e=0; e<8; ++e) b[e] = (f16)lt[(rb+8+e)*67 + c];
    f16* o = &tr[(size_t)(c0+c)*R + r0 + rb];
    *(f16x8*)o = a;
    *(f16x8*)(o+8) = b;
}

// ---------- GEMM1: 256x128 tile, BK=32, 1 phase/K-tile, 2 blocks/CU ----------
// LDS rows 64B (K=32 f16); swizzle: byte c ^= ((row&3)<<4).
__device__ __forceinline__ void stageA32(const f16* __restrict__ panel, int ld,
                                         int row0, int kcol, char* buf,
                                         int wid, int lane){
    #pragma unroll
    for (int s=0; s<2; ++s){
        int o  = s*8192 + wid*1024 + lane*16;
        int rr = o>>6;
        int c  = (o&63) ^ ((rr&3)<<4);
        gload16(panel + (size_t)(row0+rr)*ld + kcol + (c>>1), buf + s*8192 + wid*1024);
    }
}
__device__ __forceinline__ void stageB32(const f16* __restrict__ panel, int ld,
                                         int row0, int kcol, char* buf,
                                         int wid, int lane){
    int o  = wid*1024 + lane*16;
    int rr = o>>6;
    int c  = (o&63) ^ ((rr&3)<<4);
    gload16(panel + (size_t)(row0+rr)*ld + kcol + (c>>1), buf + wid*1024);
}

// GEMM1: D[b][h] = sum_i xf[b][i]*wt[h][i]; hidden[b][h]=tanh, ht=f16 micro-tiled.
__global__ __launch_bounds__(512,4) void k_gemm1(const f16* __restrict__ xf,
                                                 const f16* __restrict__ wt,
                                                 float* __restrict__ hidden,
                                                 f16* __restrict__ ht){
    __shared__ char sm[49152];            // A0 16K | A1 16K | B0 8K | B1 8K
    char* const A0 = sm;
    char* const A1 = sm + 16384;
    char* const B0 = sm + 32768;
    char* const B1 = sm + 40960;
    // XCD swizzle: nwg=1024 -> 128/XCD; 8 consecutive share btile (A-panel in L2)
    const int bid = (int)blockIdx.x;
    const int swz = (bid & 7)*128 + (bid >> 3);
    const int btile = swz >> 3, htile = swz & 7;
    const int arow0 = btile*256, brow0 = htile*128;

    const int t = threadIdx.x, lane = t & 63, wid = t >> 6;
    const int wr = wid >> 2, wc = wid & 3;
    const int fr = lane & 15, kg = lane >> 4;
    const int rowA = (wr*128 + fr)*64;
    const int rowB = (wc*32 + fr)*64;
    const int ksw  = ((kg ^ (fr & 3)) << 4);

    f32x4 acc[8][2] = {};
    f16x8 af[8], bf[2];

    stageA32(xf, II, arow0, 0, A0, wid, lane);
    stageB32(wt, II, brow0, 0, B0, wid, lane);
    asm volatile("s_waitcnt vmcnt(0)" ::: "memory");
    __builtin_amdgcn_s_barrier();

    for (int tt = 0; tt < NT1_32; ++tt){
        char* const Ac = (tt & 1) ? A1 : A0;
        char* const Bc = (tt & 1) ? B1 : B0;
        char* const An = (tt & 1) ? A0 : A1;
        char* const Bn = (tt & 1) ? B0 : B1;
        #pragma unroll
        for (int m=0;m<8;++m) af[m] = *(const f16x8*)(Ac + rowA + m*1024 + ksw);
        #pragma unroll
        for (int n=0;n<2;++n) bf[n] = *(const f16x8*)(Bc + rowB + n*1024 + ksw);
        if (tt + 1 < NT1_32){
            stageA32(xf, II, arow0, (tt+1)*32, An, wid, lane);
            stageB32(wt, II, brow0, (tt+1)*32, Bn, wid, lane);
        }
        __builtin_amdgcn_s_barrier();
        asm volatile("s_waitcnt lgkmcnt(0)" ::: "memory");
        __builtin_amdgcn_sched_barrier(0);
        __builtin_amdgcn_s_setprio(1);
        #pragma unroll
        for (int m=0;m<8;++m)
            #pragma unroll
            for (int n=0;n<2;++n)
                acc[m][n] = __builtin_amdgcn_mfma_f32_16x16x32_f16(af[m], bf[n], acc[m][n], 0, 0, 0);
        __builtin_amdgcn_s_setprio(0);
        asm volatile("s_waitcnt vmcnt(0)" ::: "memory");   // next tile's stages landed
        __builtin_amdgcn_s_barrier();
    }

    const int b_base = btile*256 + wr*128 + kg*4;
    const int h_base = htile*128 + wc*32 + fr;
    #pragma unroll
    for (int mf=0; mf<8; ++mf){
        const int b = b_base + mf*16;
        #pragma unroll
        for (int nf=0; nf<2; ++nf){
            const int h = h_base + nf*16;
            float t0 = tanh_fast(acc[mf][nf][0]);
            float t1 = tanh_fast(acc[mf][nf][1]);
            float t2 = tanh_fast(acc[mf][nf][2]);
            float t3 = tanh_fast(acc[mf][nf][3]);
            f16x4 hv = {(f16)t0,(f16)t1,(f16)t2,(f16)t3};
            *(f16x4*)&ht[(((size_t)(h>>4)*(BB>>4) + (b>>4))<<8) + ((h&15)<<4) + (b&15)] = hv;
            hidden[(size_t)(b+0)*HH + h] = t0;
            hidden[(size_t)(b+1)*HH + h] = t1;
            hidden[(size_t)(b+2)*HH + h] = t2;
            hidden[(size_t)(b+3)*HH + h] = t3;
        }
    }
}

// ---------- GEMM2 (unchanged round-11): 256x256, BK=64, 8-phase ----------
template<bool MT>
__device__ __forceinline__ void stage_half(const f16* __restrict__ panel, int ld,
                                           int row0, int kcol0, char* lds_half,
                                           int wid, int lane){
    #pragma unroll
    for (int r=0;r<2;++r){
        int o = r*8192 + wid*1024 + lane*16;
        int rr = o>>7;
        int c0 = (o&127) ^ ((rr&7)<<4);
        if constexpr (!MT){
            const f16* src = panel + (size_t)(row0 + rr)*ld + kcol0 + (c0>>1);
            gload16(src, lds_half + r*8192 + wid*1024);
        } else {
            int h    = row0 + rr;
            int babs = kcol0 + (c0>>1);
            const f16* src = panel + (((size_t)(h>>4)*(BB>>4) + (babs>>4))<<8)
                                   + ((h&15)<<4) + (babs&8);
            gload16(src, lds_half + r*8192 + wid*1024);
        }
    }
}

#define RD_A(BUFA, mh) { \
    _Pragma("unroll") for (int m_=0;m_<4;++m_){ \
        af[m_][0] = *(const f16x8*)((BUFA) + rowA + (mh)*8192 + m_*2048 + ksw0); \
        af[m_][1] = *(const f16x8*)((BUFA) + rowA + (mh)*8192 + m_*2048 + ksw1); }}

#define RD_B(BUFB, nh) { \
    _Pragma("unroll") for (int n_=0;n_<2;++n_){ \
        bf[(nh)*2+n_][0] = *(const f16x8*)((BUFB) + rowB + (nh)*4096 + n_*2048 + ksw0); \
        bf[(nh)*2+n_][1] = *(const f16x8*)((BUFB) + rowB + (nh)*4096 + n_*2048 + ksw1); }}

#define MFMA_Q(mh,nh) { \
    __builtin_amdgcn_s_setprio(1); \
    _Pragma("unroll") for (int m_=0;m_<4;++m_){ \
      _Pragma("unroll") for (int n_=0;n_<2;++n_){ \
        _Pragma("unroll") for (int ks_=0;ks_<2;++ks_){ \
          acc[(mh)*4+m_][(nh)*2+n_] = __builtin_amdgcn_mfma_f32_16x16x32_f16( \
              af[m_][ks_], bf[(nh)*2+n_][ks_], acc[(mh)*4+m_][(nh)*2+n_], 0,0,0); }}} \
    __builtin_amdgcn_s_setprio(0); }

#define PH_SYNC1 { __builtin_amdgcn_s_barrier(); \
    asm volatile("s_waitcnt lgkmcnt(0)" ::: "memory"); \
    __builtin_amdgcn_sched_barrier(0); }
#define PH_SYNC2 { __builtin_amdgcn_s_barrier(); }
#define LGKM8 { asm volatile("s_waitcnt lgkmcnt(8)" ::: "memory"); }

template<bool BMT>
__device__ __forceinline__ void kloop8(const f16* __restrict__ Ap, int lda, int arow0,
                                       const f16* __restrict__ Bp, int ldb, int brow0,
                                       int kbase, int nt, char* sm,
                                       f32x4 (&acc)[8][4])
{
    const int t = threadIdx.x, lane = t & 63, wid = t >> 6;
    const int wr = wid >> 2, wc = wid & 3;
    const int fr = lane & 15, kg = lane >> 4;
    const int mask = nt - 1;
    char* const A0 = sm;
    char* const B0 = sm + 32768;
    char* const A1 = sm + 65536;
    char* const B1 = sm + 98304;
    const int rowA = wr*16384 + fr*128;
    const int rowB = (wc>>1)*16384 + (wc&1)*8192 + fr*128;
    const int ksw0 = ((kg    ) ^ (fr & 7)) << 4;
    const int ksw1 = ((kg + 4) ^ (fr & 7)) << 4;

    f16x8 af[4][2], bf[4][2];

    stage_half<false>(Ap, lda, arow0 +   0, kbase +  0, A0,         wid, lane);
    stage_half<false>(Ap, lda, arow0 + 128, kbase +  0, A0 + 16384, wid, lane);
    stage_half<BMT  >(Bp, ldb, brow0 +   0, kbase +  0, B0,         wid, lane);
    stage_half<BMT  >(Bp, ldb, brow0 + 128, kbase +  0, B0 + 16384, wid, lane);
    stage_half<BMT  >(Bp, ldb, brow0 +   0, kbase + 64, B1,         wid, lane);
    stage_half<false>(Ap, lda, arow0 +   0, kbase + 64, A1,         wid, lane);
    asm volatile("s_waitcnt vmcnt(4)" ::: "memory");
    __builtin_amdgcn_s_barrier();

    const int ni = nt >> 1;
    for (int it = 0; it < ni; ++it){
        const int k1 = (2*it + 1) * 64;
        const int k2 = ((2*it + 2) & mask) * 64;
        const int k3 = ((2*it + 3) & mask) * 64;
        RD_A(A0, 0); RD_B(B0, 0);
        stage_half<false>(Ap, lda, arow0 + 128, kbase + k1, A1 + 16384, wid, lane);
        LGKM8; PH_SYNC1; MFMA_Q(0,0); PH_SYNC2;
        RD_B(B0, 1);
        stage_half<BMT>(Bp, ldb, brow0 + 128, kbase + k1, B1 + 16384, wid, lane);
        PH_SYNC1; MFMA_Q(0,1); PH_SYNC2;
        RD_A(A0, 1);
        stage_half<BMT>(Bp, ldb, brow0 +   0, kbase + k2, B0, wid, lane);
        PH_SYNC1; MFMA_Q(1,0); PH_SYNC2;
        stage_half<false>(Ap, lda, arow0 +   0, kbase + k2, A0, wid, lane);
        PH_SYNC1; MFMA_Q(1,1);
        asm volatile("s_waitcnt vmcnt(4)" ::: "memory");
        __builtin_amdgcn_s_barrier();
        RD_A(A1, 0); RD_B(B1, 0);
        stage_half<false>(Ap, lda, arow0 + 128, kbase + k2, A0 + 16384, wid, lane);
        LGKM8; PH_SYNC1; MFMA_Q(0,0); PH_SYNC2;
        RD_B(B1, 1);
        stage_half<BMT>(Bp, ldb, brow0 + 128, kbase + k2, B0 + 16384, wid, lane);
        PH_SYNC1; MFMA_Q(0,1); PH_SYNC2;
        RD_A(A1, 1);
        stage_half<BMT>(Bp, ldb, brow0 +   0, kbase + k3, B1, wid, lane);
        PH_SYNC1; MFMA_Q(1,0); PH_SYNC2;
        stage_half<false>(Ap, lda, arow0 +   0, kbase + k3, A1, wid, lane);
        PH_SYNC1; MFMA_Q(1,1);
        asm volatile("s_waitcnt vmcnt(4)" ::: "memory");
        __builtin_amdgcn_s_barrier();
    }
    asm volatile("s_waitcnt vmcnt(0)" ::: "memory");
    __builtin_amdgcn_s_barrier();
}

__global__ __launch_bounds__(512,2) void k_gemm2(const f16* __restrict__ xt,
                                                 const f16* __restrict__ ht,
                                                 f16* __restrict__ part){
    __shared__ char sm[131072];
    const int bid = (int)blockIdx.x;
    const int swz = (bid & 7)*32 + (bid >> 3);
    const int split = swz >> 4, tile = swz & 15;
    const int itile = tile & 3, htile = tile >> 2;
    f32x4 acc[8][4] = {};
    kloop8<true>(xt, BB, itile*256, ht, BB, htile*256, split*KCH, NT2, sm, acc);

    const int t = threadIdx.x, lane = t & 63, wid = t >> 6;
    const int wr = wid >> 2, wc = wid & 3;
    const int fr = lane & 15, kg = lane >> 4;
    const size_t pb = (size_t)split*II*HH;
    #pragma unroll
    for (int mf=0; mf<8; ++mf){
        const int i0 = itile*256 + wr*128 + mf*16 + kg*4;
        #pragma unroll
        for (int nf=0; nf<4; ++nf){
            const int h = htile*256 + wc*64 + nf*16 + fr;
            f16x4 pv = {(f16)acc[mf][nf][0],(f16)acc[mf][nf][1],
                        (f16)acc[mf][nf][2],(f16)acc[mf][nf][3]};
            *(f16x4*)&part[pb + (((size_t)(i0>>4)*(HH>>4) + (h>>4))<<8) + ((h&15)<<4) + (i0&15)] = pv;
        }
    }
}

__global__ __launch_bounds__(256) void k_final(const f16* __restrict__ part,
                                               const float* __restrict__ W,
                                               float* __restrict__ outW){
    const int T = (int)blockIdx.x*256 + threadIdx.x;   // 0..131071
    const int mt = T >> 5;
    const int hl = (T & 31) >> 1;
    const int ihalf = T & 1;
    const int i0 = (mt >> 6)*16 + ihalf*8;
    const int h  = (mt & 63)*16 + hl;
    const size_t po = ((size_t)mt << 8) + (hl << 4) + ihalf*8;
    float s[8] = {};
    #pragma unroll
    for (int sp=0; sp<SPLIT; ++sp){
        f16x8 p = __builtin_nontemporal_load((const f16x8*)&part[(size_t)sp*1048576 + po]);
        #pragma unroll
        for (int e=0;e<8;++e) s[e] += (float)p[e];
    }
    const float SCALE = 3.0517578125e-07f;  // 0.01 / 32768
    #pragma unroll
    for (int e=0;e<8;++e){
        const size_t o = (size_t)(i0+e)*HH + h;
        float r = fminf(1.f, fmaxf(-1.f, fmaf(SCALE, s[e], W[o])));
        __builtin_nontemporal_store(r, &outW[o]);
    }
}

extern "C" void kernel_launch(void* const* d_in, const int* in_sizes, int n_in,
                              void* d_out, int out_size, void* d_ws, size_t ws_size,
                              hipStream_t stream){
    (void)in_sizes; (void)n_in; (void)out_size; (void)ws_size;
    const float* x = (const float*)d_in[0];
    const float* W = (const float*)d_in[1];
    float* hidden = (float*)d_out;
    float* outW   = hidden + (size_t)BB*HH;
    char* ws = (char*)d_ws;
    // ws (194 MB, proven): xf f16 @0 (64MB) | xt f16 @64M | ht f16 (micro) @128M | wt f16 @192M
    //                      part f16 [16][I][H] (micro) @0 (32MB, overlaps dead xf)
    f16* xf   = (f16*)(ws);
    f16* xt   = (f16*)(ws + 67108864ull);
    f16* ht   = (f16*)(ws + 134217728ull);
    f16* wt   = (f16*)(ws + 201326592ull);
    f16* part = (f16*)(ws);

    k_prep2<<<dim3(528, 16), 256, 0, stream>>>(x, xf, xt, W, wt);
    k_gemm1<<<dim3((BB/256)*(HH/128)), 512, 0, stream>>>(xf, wt, hidden, ht);
    k_gemm2<<<dim3(16*SPLIT), 512, 0, stream>>>(xt, ht, part);
    k_final<<<dim3((II*HH)/(256*8)), 256, 0, stream>>>(part, W, outW);
}

// Round 13
// 214.038 us; speedup vs baseline: 1.0534x; 1.0534x over previous
//
#include <hip/hip_runtime.h>
#include <cstdint>

#define BB 32768
#define II 1024
#define HH 1024
#define SPLIT 16
#define KCH (BB/SPLIT)      // 2048
#define NT1 (II/64)         // 16 K-tiles (gemm1)
#define NT2 (KCH/64)        // 32 K-tiles per split (gemm2)

typedef _Float16 f16;
typedef _Float16 f16x4 __attribute__((ext_vector_type(4)));
typedef _Float16 f16x8 __attribute__((ext_vector_type(8)));
typedef float f32x4 __attribute__((ext_vector_type(4)));

typedef const __attribute__((address_space(1))) void gvoid_t;
typedef __attribute__((address_space(3))) void lvoid_t;

__device__ __forceinline__ void gload16(const void* g, void* l){
    __builtin_amdgcn_global_load_lds((gvoid_t*)g, (lvoid_t*)l, 16, 0, 0);
}

__device__ __forceinline__ float tanh_fast(float s){
    float a = fabsf(s);
    float e = __expf(-2.0f * a);
    float t = __fdividef(1.0f - e, 1.0f + e);
    return s < 0.0f ? -t : t;
}

// Fused prep: blocks [0,512): x [B][I] -> xf f16 + xt f16 [I][B]
//             blocks [512,528): W [I][H] -> wt f16 [H][I]
__global__ __launch_bounds__(256) void k_prep2(const float* __restrict__ x,
                                               f16* __restrict__ xf,
                                               f16* __restrict__ xt,
                                               const float* __restrict__ W,
                                               f16* __restrict__ wt){
    __shared__ float lt[64*67];
    const int t = threadIdx.x;
    const int bx = (int)blockIdx.x;
    const float* in; f16* cvt; f16* tr; int C, R, r0;
    if (bx < 512){ in = x; cvt = xf; tr = xt; C = II; R = BB; r0 = bx*64; }
    else         { in = W; cvt = nullptr; tr = wt; C = HH; R = II; r0 = (bx-512)*64; }
    const int c0 = blockIdx.y*64;
    #pragma unroll
    for (int p=0; p<4; ++p){
        int r = p*16 + (t>>4);
        int c = (t&15)*4;
        f32x4 v = __builtin_nontemporal_load((const f32x4*)&in[(size_t)(r0+r)*C + c0 + c]);
        if (cvt){
            f16x4 hv = {(f16)v[0],(f16)v[1],(f16)v[2],(f16)v[3]};
            *(f16x4*)&cvt[(size_t)(r0+r)*C + c0 + c] = hv;
        }
        lt[r*67 + c+0] = v[0];
        lt[r*67 + c+1] = v[1];
        lt[r*67 + c+2] = v[2];
        lt[r*67 + c+3] = v[3];
    }
    __syncthreads();
    const int c = t>>2, rb = (t&3)*16;
    f16x8 a, b;
    #pragma unroll
    for (int e=0; e<8; ++e) a[e] = (f16)lt[(rb+e)*67 + c];
    #pragma unroll
    for (int e=0; e<8; ++e) b[e] = (f16)lt[(rb+8+e)*67 + c];
    f16* o = &tr[(size_t)(c0+c)*R + r0 + rb];
    *(f16x8*)o = a;
    *(f16x8*)(o+8) = b;
}

// stage one 128x64-f16 half-tile (16KB) into linear LDS, source inverse-swizzled.
// LDS image byte b: row = b>>7, col c = (b&127) ^ (((b>>7)&7)<<4).
// MT=false: panel flat [row][ld] k-major. MT=true: 16x16 micro-tiled
// [h>>4][b>>4][h&15][b&15] f16.
template<bool MT>
__device__ __forceinline__ void stage_half(const f16* __restrict__ panel, int ld,
                                           int row0, int kcol0, char* lds_half,
                                           int wid, int lane){
    #pragma unroll
    for (int r=0;r<2;++r){
        int o = r*8192 + wid*1024 + lane*16;
        int rr = o>>7;
        int c0 = (o&127) ^ ((rr&7)<<4);
        if constexpr (!MT){
            const f16* src = panel + (size_t)(row0 + rr)*ld + kcol0 + (c0>>1);
            gload16(src, lds_half + r*8192 + wid*1024);
        } else {
            int h    = row0 + rr;
            int babs = kcol0 + (c0>>1);
            const f16* src = panel + (((size_t)(h>>4)*(BB>>4) + (babs>>4))<<8)
                                   + ((h&15)<<4) + (babs&8);
            gload16(src, lds_half + r*8192 + wid*1024);
        }
    }
}

#define RD_A(BUFA, mh) { \
    _Pragma("unroll") for (int m_=0;m_<4;++m_){ \
        af[m_][0] = *(const f16x8*)((BUFA) + rowA + (mh)*8192 + m_*2048 + ksw0); \
        af[m_][1] = *(const f16x8*)((BUFA) + rowA + (mh)*8192 + m_*2048 + ksw1); }}

#define RD_B(BUFB, nh) { \
    _Pragma("unroll") for (int n_=0;n_<2;++n_){ \
        bf[(nh)*2+n_][0] = *(const f16x8*)((BUFB) + rowB + (nh)*4096 + n_*2048 + ksw0); \
        bf[(nh)*2+n_][1] = *(const f16x8*)((BUFB) + rowB + (nh)*4096 + n_*2048 + ksw1); }}

#define MFMA_Q(mh,nh) { \
    __builtin_amdgcn_s_setprio(1); \
    _Pragma("unroll") for (int m_=0;m_<4;++m_){ \
      _Pragma("unroll") for (int n_=0;n_<2;++n_){ \
        _Pragma("unroll") for (int ks_=0;ks_<2;++ks_){ \
          acc[(mh)*4+m_][(nh)*2+n_] = __builtin_amdgcn_mfma_f32_16x16x32_f16( \
              af[m_][ks_], bf[(nh)*2+n_][ks_], acc[(mh)*4+m_][(nh)*2+n_], 0,0,0); }}} \
    __builtin_amdgcn_s_setprio(0); }

#define PH_SYNC1 { __builtin_amdgcn_s_barrier(); \
    asm volatile("s_waitcnt lgkmcnt(0)" ::: "memory"); \
    __builtin_amdgcn_sched_barrier(0); }
#define PH_SYNC2 { __builtin_amdgcn_s_barrier(); }
#define LGKM8 { asm volatile("s_waitcnt lgkmcnt(8)" ::: "memory"); }

// 256x256 tile, BK=64, 8 waves, 8-phase pipelined K-loop (T2+T3+T4+T5).
template<bool BMT>
__device__ __forceinline__ void kloop8(const f16* __restrict__ Ap, int lda, int arow0,
                                       const f16* __restrict__ Bp, int ldb, int brow0,
                                       int kbase, int nt, char* sm,
                                       f32x4 (&acc)[8][4])
{
    const int t = threadIdx.x, lane = t & 63, wid = t >> 6;
    const int wr = wid >> 2, wc = wid & 3;
    const int fr = lane & 15, kg = lane >> 4;
    const int mask = nt - 1;
    char* const A0 = sm;
    char* const B0 = sm + 32768;
    char* const A1 = sm + 65536;
    char* const B1 = sm + 98304;
    const int rowA = wr*16384 + fr*128;
    const int rowB = (wc>>1)*16384 + (wc&1)*8192 + fr*128;
    const int ksw0 = ((kg    ) ^ (fr & 7)) << 4;
    const int ksw1 = ((kg + 4) ^ (fr & 7)) << 4;

    f16x8 af[4][2], bf[4][2];

    stage_half<false>(Ap, lda, arow0 +   0, kbase +  0, A0,         wid, lane);
    stage_half<false>(Ap, lda, arow0 + 128, kbase +  0, A0 + 16384, wid, lane);
    stage_half<BMT  >(Bp, ldb, brow0 +   0, kbase +  0, B0,         wid, lane);
    stage_half<BMT  >(Bp, ldb, brow0 + 128, kbase +  0, B0 + 16384, wid, lane);
    stage_half<BMT  >(Bp, ldb, brow0 +   0, kbase + 64, B1,         wid, lane);
    stage_half<false>(Ap, lda, arow0 +   0, kbase + 64, A1,         wid, lane);
    asm volatile("s_waitcnt vmcnt(4)" ::: "memory");
    __builtin_amdgcn_s_barrier();

    const int ni = nt >> 1;
    for (int it = 0; it < ni; ++it){
        const int k1 = (2*it + 1) * 64;
        const int k2 = ((2*it + 2) & mask) * 64;
        const int k3 = ((2*it + 3) & mask) * 64;
        RD_A(A0, 0); RD_B(B0, 0);
        stage_half<false>(Ap, lda, arow0 + 128, kbase + k1, A1 + 16384, wid, lane);
        LGKM8; PH_SYNC1; MFMA_Q(0,0); PH_SYNC2;
        RD_B(B0, 1);
        stage_half<BMT>(Bp, ldb, brow0 + 128, kbase + k1, B1 + 16384, wid, lane);
        PH_SYNC1; MFMA_Q(0,1); PH_SYNC2;
        RD_A(A0, 1);
        stage_half<BMT>(Bp, ldb, brow0 +   0, kbase + k2, B0, wid, lane);
        PH_SYNC1; MFMA_Q(1,0); PH_SYNC2;
        stage_half<false>(Ap, lda, arow0 +   0, kbase + k2, A0, wid, lane);
        PH_SYNC1; MFMA_Q(1,1);
        asm volatile("s_waitcnt vmcnt(4)" ::: "memory");
        __builtin_amdgcn_s_barrier();
        RD_A(A1, 0); RD_B(B1, 0);
        stage_half<false>(Ap, lda, arow0 + 128, kbase + k2, A0 + 16384, wid, lane);
        LGKM8; PH_SYNC1; MFMA_Q(0,0); PH_SYNC2;
        RD_B(B1, 1);
        stage_half<BMT>(Bp, ldb, brow0 + 128, kbase + k2, B0 + 16384, wid, lane);
        PH_SYNC1; MFMA_Q(0,1); PH_SYNC2;
        RD_A(A1, 1);
        stage_half<BMT>(Bp, ldb, brow0 +   0, kbase + k3, B1, wid, lane);
        PH_SYNC1; MFMA_Q(1,0); PH_SYNC2;
        stage_half<false>(Ap, lda, arow0 +   0, kbase + k3, A1, wid, lane);
        PH_SYNC1; MFMA_Q(1,1);
        asm volatile("s_waitcnt vmcnt(4)" ::: "memory");
        __builtin_amdgcn_s_barrier();
    }
    asm volatile("s_waitcnt vmcnt(0)" ::: "memory");
    __builtin_amdgcn_s_barrier();
}

// GEMM1: D[b][h] = sum_i xf[b][i]*wt[h][i]; hidden[b][h]=tanh, ht=f16 micro-tiled.
// Epilogue: tanh in-place; ht direct f16x4; hidden via LDS bounce -> f32x4 stores
// (4x fewer VMEM store instructions; DS pipe does the transpose).
__global__ __launch_bounds__(512,2) void k_gemm1(const f16* __restrict__ xf,
                                                 const f16* __restrict__ wt,
                                                 float* __restrict__ hidden,
                                                 f16* __restrict__ ht){
    __shared__ char sm[131072];
    const int bid = (int)blockIdx.x;
    const int swz = (bid & 7)*64 + (bid >> 3);
    const int btile = swz >> 2, htile = swz & 3;
    f32x4 acc[8][4] = {};
    kloop8<false>(xf, II, btile*256, wt, II, htile*256, 0, NT1, sm, acc);

    const int t = threadIdx.x, lane = t & 63, wid = t >> 6;
    const int wr = wid >> 2, wc = wid & 3;
    const int fr = lane & 15, kg = lane >> 4;

    // tanh once, in place
    #pragma unroll
    for (int mf=0; mf<8; ++mf)
        #pragma unroll
        for (int nf=0; nf<4; ++nf)
            #pragma unroll
            for (int q=0;q<4;++q)
                acc[mf][nf][q] = tanh_fast(acc[mf][nf][q]);

    // ht micro-tile stores (contiguous 512B wave-stores)
    const int b_base = btile*256 + wr*128 + kg*4;
    const int h_base = htile*256 + wc*64 + fr;
    #pragma unroll
    for (int mf=0; mf<8; ++mf){
        const int b = b_base + mf*16;
        #pragma unroll
        for (int nf=0; nf<4; ++nf){
            const int h = h_base + nf*16;
            f16x4 hv = {(f16)acc[mf][nf][0],(f16)acc[mf][nf][1],
                        (f16)acc[mf][nf][2],(f16)acc[mf][nf][3]};
            *(f16x4*)&ht[(((size_t)(h>>4)*(BB>>4) + (b>>4))<<8) + ((h&15)<<4) + (b&15)] = hv;
        }
    }

    // hidden via LDS bounce: slab [128 b][256 h] f32 = 128KB, 2 passes over wr
    float* Lf = (float*)sm;
    const int bl_w = kg*4;                       // + mf*16 (+q)
    const int h_w  = wc*64 + fr;                 // + nf*16
    #pragma unroll
    for (int p=0; p<2; ++p){
        if (wr == p){
            #pragma unroll
            for (int mf=0; mf<8; ++mf)
                #pragma unroll
                for (int nf=0; nf<4; ++nf)
                    #pragma unroll
                    for (int q=0;q<4;++q)
                        Lf[(mf*16 + bl_w + q)*256 + h_w + nf*16] = acc[mf][nf][q];
        }
        __syncthreads();
        {
            const int bl = t >> 2;               // 0..127
            const size_t row = (size_t)(btile*256 + p*128 + bl)*HH + htile*256;
            #pragma unroll
            for (int k=0;k<16;++k){
                const int c = (t & 3) + 4*k;     // 0..63 float4 chunks
                f32x4 v = *(const f32x4*)&Lf[bl*256 + c*4];
                *(f32x4*)&hidden[row + c*4] = v;
            }
        }
        __syncthreads();
    }
}

// GEMM2: part[split] = xt-chunk @ ht-chunk^T, part micro-tiled [i>>4][h>>4][h&15][i&15].
__global__ __launch_bounds__(512,2) void k_gemm2(const f16* __restrict__ xt,
                                                 const f16* __restrict__ ht,
                                                 f16* __restrict__ part){
    __shared__ char sm[131072];
    const int bid = (int)blockIdx.x;
    const int swz = (bid & 7)*32 + (bid >> 3);
    const int split = swz >> 4, tile = swz & 15;
    const int itile = tile & 3, htile = tile >> 2;
    f32x4 acc[8][4] = {};
    kloop8<true>(xt, BB, itile*256, ht, BB, htile*256, split*KCH, NT2, sm, acc);

    const int t = threadIdx.x, lane = t & 63, wid = t >> 6;
    const int wr = wid >> 2, wc = wid & 3;
    const int fr = lane & 15, kg = lane >> 4;
    const size_t pb = (size_t)split*II*HH;
    #pragma unroll
    for (int mf=0; mf<8; ++mf){
        const int i0 = itile*256 + wr*128 + mf*16 + kg*4;
        #pragma unroll
        for (int nf=0; nf<4; ++nf){
            const int h = htile*256 + wc*64 + nf*16 + fr;
            f16x4 pv = {(f16)acc[mf][nf][0],(f16)acc[mf][nf][1],
                        (f16)acc[mf][nf][2],(f16)acc[mf][nf][3]};
            *(f16x4*)&part[pb + (((size_t)(i0>>4)*(HH>>4) + (h>>4))<<8) + ((h&15)<<4) + (i0&15)] = pv;
        }
    }
}

__global__ __launch_bounds__(256) void k_final(const f16* __restrict__ part,
                                               const float* __restrict__ W,
                                               float* __restrict__ outW){
    const int T = (int)blockIdx.x*256 + threadIdx.x;   // 0..131071
    const int mt = T >> 5;
    const int hl = (T & 31) >> 1;
    const int ihalf = T & 1;
    const int i0 = (mt >> 6)*16 + ihalf*8;
    const int h  = (mt & 63)*16 + hl;
    const size_t po = ((size_t)mt << 8) + (hl << 4) + ihalf*8;
    float s[8] = {};
    #pragma unroll
    for (int sp=0; sp<SPLIT; ++sp){
        f16x8 p = __builtin_nontemporal_load((const f16x8*)&part[(size_t)sp*1048576 + po]);
        #pragma unroll
        for (int e=0;e<8;++e) s[e] += (float)p[e];
    }
    const float SCALE = 3.0517578125e-07f;  // 0.01 / 32768
    #pragma unroll
    for (int e=0;e<8;++e){
        const size_t o = (size_t)(i0+e)*HH + h;
        float r = fminf(1.f, fmaxf(-1.f, fmaf(SCALE, s[e], W[o])));
        __builtin_nontemporal_store(r, &outW[o]);
    }
}

extern "C" void kernel_launch(void* const* d_in, const int* in_sizes, int n_in,
                              void* d_out, int out_size, void* d_ws, size_t ws_size,
                              hipStream_t stream){
    (void)in_sizes; (void)n_in; (void)out_size; (void)ws_size;
    const float* x = (const float*)d_in[0];
    const float* W = (const float*)d_in[1];
    float* hidden = (float*)d_out;
    float* outW   = hidden + (size_t)BB*HH;
    char* ws = (char*)d_ws;
    // ws (194 MB, proven): xf f16 @0 (64MB) | xt f16 @64M | ht f16 (micro) @128M | wt f16 @192M
    //                      part f16 [16][I][H] (micro) @0 (32MB, overlaps dead xf)
    f16* xf   = (f16*)(ws);
    f16* xt   = (f16*)(ws + 67108864ull);
    f16* ht   = (f16*)(ws + 134217728ull);
    f16* wt   = (f16*)(ws + 201326592ull);
    f16* part = (f16*)(ws);

    k_prep2<<<dim3(528, 16), 256, 0, stream>>>(x, xf, xt, W, wt);
    k_gemm1<<<dim3((BB/256)*(HH/256)), 512, 0, stream>>>(xf, wt, hidden, ht);
    k_gemm2<<<dim3(16*SPLIT), 512, 0, stream>>>(xt, ht, part);
    k_final<<<dim3((II*HH)/(256*8)), 256, 0, stream>>>(part, W, outW);
}

// Round 14
// 195.173 us; speedup vs baseline: 1.1552x; 1.0967x over previous
//
#include <hip/hip_runtime.h>
#include <hip/hip_fp8.h>
#include <cstdint>

#define BB 32768
#define II 1024
#define HH 1024
#define SPLIT 16
#define KCH (BB/SPLIT)      // 2048
#define NT1 (II/64)         // 16 K-tiles (gemm1)
#define NT2 (KCH/64)        // 32 K-tiles per split (gemm2)

typedef _Float16 f16;
typedef _Float16 f16x4 __attribute__((ext_vector_type(4)));
typedef _Float16 f16x8 __attribute__((ext_vector_type(8)));
typedef float f32x4 __attribute__((ext_vector_type(4)));

typedef const __attribute__((address_space(1))) void gvoid_t;
typedef __attribute__((address_space(3))) void lvoid_t;

__device__ __forceinline__ void gload16(const void* g, void* l){
    __builtin_amdgcn_global_load_lds((gvoid_t*)g, (lvoid_t*)l, 16, 0, 0);
}

__device__ __forceinline__ float tanh_fast(float s){
    float a = fabsf(s);
    float e = __expf(-2.0f * a);
    float t = __fdividef(1.0f - e, 1.0f + e);
    return s < 0.0f ? -t : t;
}

__device__ __forceinline__ unsigned char f2fp8(float v){
    __hip_fp8_e4m3 q(v);
    return (unsigned char)q.__x;
}

// Fused prep: blocks [0,512): x [B][I] -> xf f16 + xt8 fp8 [I][B]
//             blocks [512,528): W [I][H] -> wt f16 [H][I]
__global__ __launch_bounds__(256) void k_prep2(const float* __restrict__ x,
                                               f16* __restrict__ xf,
                                               unsigned char* __restrict__ xt8,
                                               const float* __restrict__ W,
                                               f16* __restrict__ wt){
    __shared__ float lt[64*67];
    const int t = threadIdx.x;
    const int bx = (int)blockIdx.x;
    const bool isX = (bx < 512);
    const float* in = isX ? x : W;
    const int C = isX ? II : HH, R = isX ? BB : II;
    const int r0 = (isX ? bx : bx-512)*64;
    const int c0 = blockIdx.y*64;
    #pragma unroll
    for (int p=0; p<4; ++p){
        int r = p*16 + (t>>4);
        int c = (t&15)*4;
        f32x4 v = __builtin_nontemporal_load((const f32x4*)&in[(size_t)(r0+r)*C + c0 + c]);
        if (isX){
            f16x4 hv = {(f16)v[0],(f16)v[1],(f16)v[2],(f16)v[3]};
            *(f16x4*)&xf[(size_t)(r0+r)*C + c0 + c] = hv;
        }
        lt[r*67 + c+0] = v[0];
        lt[r*67 + c+1] = v[1];
        lt[r*67 + c+2] = v[2];
        lt[r*67 + c+3] = v[3];
    }
    __syncthreads();
    const int c = t>>2, rb = (t&3)*16;
    if (isX){
        union { unsigned char cb[16]; f32x4 v4; } u;
        #pragma unroll
        for (int e=0; e<16; ++e) u.cb[e] = f2fp8(lt[(rb+e)*67 + c]);
        *(f32x4*)&xt8[(size_t)(c0+c)*R + r0 + rb] = u.v4;
    } else {
        f16x8 a, b;
        #pragma unroll
        for (int e=0; e<8; ++e) a[e] = (f16)lt[(rb+e)*67 + c];
        #pragma unroll
        for (int e=0; e<8; ++e) b[e] = (f16)lt[(rb+8+e)*67 + c];
        f16* o = &wt[(size_t)(c0+c)*R + r0 + rb];
        *(f16x8*)o = a;
        *(f16x8*)(o+8) = b;
    }
}

// ================= GEMM1 (f16, round-11 structure) =================
__device__ __forceinline__ void stage_half(const f16* __restrict__ panel, int ld,
                                           int row0, int kcol0, char* lds_half,
                                           int wid, int lane){
    #pragma unroll
    for (int r=0;r<2;++r){
        int o = r*8192 + wid*1024 + lane*16;
        int rr = o>>7;
        int c0 = (o&127) ^ ((rr&7)<<4);
        gload16(panel + (size_t)(row0 + rr)*ld + kcol0 + (c0>>1), lds_half + r*8192 + wid*1024);
    }
}

#define RD_A(BUFA, mh) { \
    _Pragma("unroll") for (int m_=0;m_<4;++m_){ \
        af[m_][0] = *(const f16x8*)((BUFA) + rowA + (mh)*8192 + m_*2048 + ksw0); \
        af[m_][1] = *(const f16x8*)((BUFA) + rowA + (mh)*8192 + m_*2048 + ksw1); }}

#define RD_B(BUFB, nh) { \
    _Pragma("unroll") for (int n_=0;n_<2;++n_){ \
        bf[(nh)*2+n_][0] = *(const f16x8*)((BUFB) + rowB + (nh)*4096 + n_*2048 + ksw0); \
        bf[(nh)*2+n_][1] = *(const f16x8*)((BUFB) + rowB + (nh)*4096 + n_*2048 + ksw1); }}

#define MFMA_Q(mh,nh) { \
    __builtin_amdgcn_s_setprio(1); \
    _Pragma("unroll") for (int m_=0;m_<4;++m_){ \
      _Pragma("unroll") for (int n_=0;n_<2;++n_){ \
        _Pragma("unroll") for (int ks_=0;ks_<2;++ks_){ \
          acc[(mh)*4+m_][(nh)*2+n_] = __builtin_amdgcn_mfma_f32_16x16x32_f16( \
              af[m_][ks_], bf[(nh)*2+n_][ks_], acc[(mh)*4+m_][(nh)*2+n_], 0,0,0); }}} \
    __builtin_amdgcn_s_setprio(0); }

#define PH_SYNC1 { __builtin_amdgcn_s_barrier(); \
    asm volatile("s_waitcnt lgkmcnt(0)" ::: "memory"); \
    __builtin_amdgcn_sched_barrier(0); }
#define PH_SYNC2 { __builtin_amdgcn_s_barrier(); }
#define LGKM8 { asm volatile("s_waitcnt lgkmcnt(8)" ::: "memory"); }

__device__ __forceinline__ void kloop8_f16(const f16* __restrict__ Ap, int lda, int arow0,
                                           const f16* __restrict__ Bp, int ldb, int brow0,
                                           int kbase, int nt, char* sm,
                                           f32x4 (&acc)[8][4])
{
    const int t = threadIdx.x, lane = t & 63, wid = t >> 6;
    const int wr = wid >> 2, wc = wid & 3;
    const int fr = lane & 15, kg = lane >> 4;
    const int mask = nt - 1;
    char* const A0 = sm;
    char* const B0 = sm + 32768;
    char* const A1 = sm + 65536;
    char* const B1 = sm + 98304;
    const int rowA = wr*16384 + fr*128;
    const int rowB = (wc>>1)*16384 + (wc&1)*8192 + fr*128;
    const int ksw0 = ((kg    ) ^ (fr & 7)) << 4;
    const int ksw1 = ((kg + 4) ^ (fr & 7)) << 4;

    f16x8 af[4][2], bf[4][2];

    stage_half(Ap, lda, arow0 +   0, kbase +  0, A0,         wid, lane);
    stage_half(Ap, lda, arow0 + 128, kbase +  0, A0 + 16384, wid, lane);
    stage_half(Bp, ldb, brow0 +   0, kbase +  0, B0,         wid, lane);
    stage_half(Bp, ldb, brow0 + 128, kbase +  0, B0 + 16384, wid, lane);
    stage_half(Bp, ldb, brow0 +   0, kbase + 64, B1,         wid, lane);
    stage_half(Ap, lda, arow0 +   0, kbase + 64, A1,         wid, lane);
    asm volatile("s_waitcnt vmcnt(4)" ::: "memory");
    __builtin_amdgcn_s_barrier();

    const int ni = nt >> 1;
    for (int it = 0; it < ni; ++it){
        const int k1 = (2*it + 1) * 64;
        const int k2 = ((2*it + 2) & mask) * 64;
        const int k3 = ((2*it + 3) & mask) * 64;
        RD_A(A0, 0); RD_B(B0, 0);
        stage_half(Ap, lda, arow0 + 128, kbase + k1, A1 + 16384, wid, lane);
        LGKM8; PH_SYNC1; MFMA_Q(0,0); PH_SYNC2;
        RD_B(B0, 1);
        stage_half(Bp, ldb, brow0 + 128, kbase + k1, B1 + 16384, wid, lane);
        PH_SYNC1; MFMA_Q(0,1); PH_SYNC2;
        RD_A(A0, 1);
        stage_half(Bp, ldb, brow0 +   0, kbase + k2, B0, wid, lane);
        PH_SYNC1; MFMA_Q(1,0); PH_SYNC2;
        stage_half(Ap, lda, arow0 +   0, kbase + k2, A0, wid, lane);
        PH_SYNC1; MFMA_Q(1,1);
        asm volatile("s_waitcnt vmcnt(4)" ::: "memory");
        __builtin_amdgcn_s_barrier();
        RD_A(A1, 0); RD_B(B1, 0);
        stage_half(Ap, lda, arow0 + 128, kbase + k2, A0 + 16384, wid, lane);
        LGKM8; PH_SYNC1; MFMA_Q(0,0); PH_SYNC2;
        RD_B(B1, 1);
        stage_half(Bp, ldb, brow0 + 128, kbase + k2, B0 + 16384, wid, lane);
        PH_SYNC1; MFMA_Q(0,1); PH_SYNC2;
        RD_A(A1, 1);
        stage_half(Bp, ldb, brow0 +   0, kbase + k3, B1, wid, lane);
        PH_SYNC1; MFMA_Q(1,0); PH_SYNC2;
        stage_half(Ap, lda, arow0 +   0, kbase + k3, A1, wid, lane);
        PH_SYNC1; MFMA_Q(1,1);
        asm volatile("s_waitcnt vmcnt(4)" ::: "memory");
        __builtin_amdgcn_s_barrier();
    }
    asm volatile("s_waitcnt vmcnt(0)" ::: "memory");
    __builtin_amdgcn_s_barrier();
}

// GEMM1: hidden[b][h]=tanh(xf·wt); ht8 = fp8(tanh) micro-tiled [h>>4][b>>4][h&15][b&15].
__global__ __launch_bounds__(512,2) void k_gemm1(const f16* __restrict__ xf,
                                                 const f16* __restrict__ wt,
                                                 float* __restrict__ hidden,
                                                 unsigned char* __restrict__ ht8){
    __shared__ char sm[131072];
    const int bid = (int)blockIdx.x;
    const int swz = (bid & 7)*64 + (bid >> 3);
    const int btile = swz >> 2, htile = swz & 3;
    f32x4 acc[8][4] = {};
    kloop8_f16(xf, II, btile*256, wt, II, htile*256, 0, NT1, sm, acc);

    const int t = threadIdx.x, lane = t & 63, wid = t >> 6;
    const int wr = wid >> 2, wc = wid & 3;
    const int fr = lane & 15, kg = lane >> 4;
    const int b_base = btile*256 + wr*128 + kg*4;
    const int h_base = htile*256 + wc*64 + fr;
    #pragma unroll
    for (int mf=0; mf<8; ++mf){
        const int b = b_base + mf*16;
        #pragma unroll
        for (int nf=0; nf<4; ++nf){
            const int h = h_base + nf*16;
            float t0 = tanh_fast(acc[mf][nf][0]);
            float t1 = tanh_fast(acc[mf][nf][1]);
            float t2 = tanh_fast(acc[mf][nf][2]);
            float t3 = tanh_fast(acc[mf][nf][3]);
            union { unsigned char cb[4]; unsigned int u; } p;
            p.cb[0] = f2fp8(t0); p.cb[1] = f2fp8(t1);
            p.cb[2] = f2fp8(t2); p.cb[3] = f2fp8(t3);
            *(unsigned int*)&ht8[(((size_t)(h>>4)*(BB>>4) + (b>>4))<<8) + ((h&15)<<4) + (b&15)] = p.u;
            hidden[(size_t)(b+0)*HH + h] = t0;
            hidden[(size_t)(b+1)*HH + h] = t1;
            hidden[(size_t)(b+2)*HH + h] = t2;
            hidden[(size_t)(b+3)*HH + h] = t3;
        }
    }
}

// ================= GEMM2 (fp8) =================
// LDS rows 64B (K=64 fp8). Read swizzle on 8B granules: gi ^= (row&6)
// (even XOR keeps gload16's 16B source pairs contiguous).
// MT=false: flat [row][ld] fp8. MT=true: 16x16 fp8 micro-tiles (256B).
template<bool MT>
__device__ __forceinline__ void stage_half8(const unsigned char* __restrict__ panel, int ld,
                                            int row0, int kcol0, char* lds_half,
                                            int wid, int lane){
    int o  = wid*1024 + lane*16;
    int rr = o>>6;
    int c  = (o&63) ^ ((rr&6)<<3);
    if constexpr (!MT){
        gload16(panel + (size_t)(row0+rr)*ld + kcol0 + c, lds_half + wid*1024);
    } else {
        int h = row0 + rr;
        int babs = kcol0 + c;
        gload16(panel + (((size_t)(h>>4)*(BB>>4) + (babs>>4))<<8) + ((h&15)<<4) + (babs&15),
                lds_half + wid*1024);
    }
}

#define RD_A8(BUFA, mh) { \
    _Pragma("unroll") for (int m_=0;m_<4;++m_){ \
        afl[m_][0] = *(const long*)((BUFA) + rowA8 + (mh)*4096 + m_*1024 + k80); \
        afl[m_][1] = *(const long*)((BUFA) + rowA8 + (mh)*4096 + m_*1024 + k81); }}

#define RD_B8(BUFB, nh) { \
    _Pragma("unroll") for (int n_=0;n_<2;++n_){ \
        bfl[(nh)*2+n_][0] = *(const long*)((BUFB) + rowB8 + (nh)*2048 + n_*1024 + k80); \
        bfl[(nh)*2+n_][1] = *(const long*)((BUFB) + rowB8 + (nh)*2048 + n_*1024 + k81); }}

#define MFMA_Q8(mh,nh) { \
    __builtin_amdgcn_s_setprio(1); \
    _Pragma("unroll") for (int m_=0;m_<4;++m_){ \
      _Pragma("unroll") for (int n_=0;n_<2;++n_){ \
        _Pragma("unroll") for (int ks_=0;ks_<2;++ks_){ \
          acc[(mh)*4+m_][(nh)*2+n_] = __builtin_amdgcn_mfma_f32_16x16x32_fp8_fp8( \
              afl[m_][ks_], bfl[(nh)*2+n_][ks_], acc[(mh)*4+m_][(nh)*2+n_], 0,0,0); }}} \
    __builtin_amdgcn_s_setprio(0); }

// GEMM2: part[split] = xt8-chunk · ht8-chunk^T; part f16 micro-tiled.
__global__ __launch_bounds__(512,2) void k_gemm2(const unsigned char* __restrict__ xt8,
                                                 const unsigned char* __restrict__ ht8,
                                                 f16* __restrict__ part){
    __shared__ char sm[65536];           // A0 16K | B0 16K | A1 16K | B1 16K
    const int bid = (int)blockIdx.x;
    const int swz = (bid & 7)*32 + (bid >> 3);
    const int split = swz >> 4, tile = swz & 15;
    const int itile = tile & 3, htile = tile >> 2;
    const int arow0 = itile*256, brow0 = htile*256, kbase = split*KCH;

    const int t = threadIdx.x, lane = t & 63, wid = t >> 6;
    const int wr = wid >> 2, wc = wid & 3;
    const int fr = lane & 15, kg = lane >> 4;
    const int mask = NT2 - 1;
    char* const A0 = sm;
    char* const B0 = sm + 16384;
    char* const A1 = sm + 32768;
    char* const B1 = sm + 49152;
    const int rowA8 = wr*8192 + fr*64;
    const int rowB8 = (wc>>1)*8192 + (wc&1)*4096 + fr*64;
    const int s6  = fr & 6;
    const int k80 = ((kg    ) ^ s6) << 3;
    const int k81 = ((kg + 4) ^ s6) << 3;

    f32x4 acc[8][4] = {};
    long afl[4][2], bfl[4][2];

    stage_half8<false>(xt8, BB, arow0 +   0, kbase +  0, A0,        wid, lane);
    stage_half8<false>(xt8, BB, arow0 + 128, kbase +  0, A0 + 8192, wid, lane);
    stage_half8<true >(ht8, BB, brow0 +   0, kbase +  0, B0,        wid, lane);
    stage_half8<true >(ht8, BB, brow0 + 128, kbase +  0, B0 + 8192, wid, lane);
    stage_half8<true >(ht8, BB, brow0 +   0, kbase + 64, B1,        wid, lane);
    stage_half8<false>(xt8, BB, arow0 +   0, kbase + 64, A1,        wid, lane);
    asm volatile("s_waitcnt vmcnt(2)" ::: "memory");
    __builtin_amdgcn_s_barrier();

    const int ni = NT2 >> 1;
    for (int it = 0; it < ni; ++it){
        const int k1 = (2*it + 1) * 64;
        const int k2 = ((2*it + 2) & mask) * 64;
        const int k3 = ((2*it + 3) & mask) * 64;
        RD_A8(A0, 0); RD_B8(B0, 0);
        stage_half8<false>(xt8, BB, arow0 + 128, kbase + k1, A1 + 8192, wid, lane);
        PH_SYNC1; MFMA_Q8(0,0); PH_SYNC2;
        RD_B8(B0, 1);
        stage_half8<true>(ht8, BB, brow0 + 128, kbase + k1, B1 + 8192, wid, lane);
        PH_SYNC1; MFMA_Q8(0,1); PH_SYNC2;
        RD_A8(A0, 1);
        stage_half8<true>(ht8, BB, brow0 +   0, kbase + k2, B0, wid, lane);
        PH_SYNC1; MFMA_Q8(1,0); PH_SYNC2;
        stage_half8<false>(xt8, BB, arow0 +   0, kbase + k2, A0, wid, lane);
        PH_SYNC1; MFMA_Q8(1,1);
        asm volatile("s_waitcnt vmcnt(2)" ::: "memory");
        __builtin_amdgcn_s_barrier();
        RD_A8(A1, 0); RD_B8(B1, 0);
        stage_half8<false>(xt8, BB, arow0 + 128, kbase + k2, A0 + 8192, wid, lane);
        PH_SYNC1; MFMA_Q8(0,0); PH_SYNC2;
        RD_B8(B1, 1);
        stage_half8<true>(ht8, BB, brow0 + 128, kbase + k2, B0 + 8192, wid, lane);
        PH_SYNC1; MFMA_Q8(0,1); PH_SYNC2;
        RD_A8(A1, 1);
        stage_half8<true>(ht8, BB, brow0 +   0, kbase + k3, B1, wid, lane);
        PH_SYNC1; MFMA_Q8(1,0); PH_SYNC2;
        stage_half8<false>(xt8, BB, arow0 +   0, kbase + k3, A1, wid, lane);
        PH_SYNC1; MFMA_Q8(1,1);
        asm volatile("s_waitcnt vmcnt(2)" ::: "memory");
        __builtin_amdgcn_s_barrier();
    }
    asm volatile("s_waitcnt vmcnt(0)" ::: "memory");
    __builtin_amdgcn_s_barrier();

    const size_t pb = (size_t)split*II*HH;
    #pragma unroll
    for (int mf=0; mf<8; ++mf){
        const int i0 = itile*256 + wr*128 + mf*16 + kg*4;
        #pragma unroll
        for (int nf=0; nf<4; ++nf){
            const int h = htile*256 + wc*64 + nf*16 + fr;
            f16x4 pv = {(f16)acc[mf][nf][0],(f16)acc[mf][nf][1],
                        (f16)acc[mf][nf][2],(f16)acc[mf][nf][3]};
            *(f16x4*)&part[pb + (((size_t)(i0>>4)*(HH>>4) + (h>>4))<<8) + ((h&15)<<4) + (i0&15)] = pv;
        }
    }
}

__global__ __launch_bounds__(256) void k_final(const f16* __restrict__ part,
                                               const float* __restrict__ W,
                                               float* __restrict__ outW){
    const int T = (int)blockIdx.x*256 + threadIdx.x;   // 0..131071
    const int mt = T >> 5;
    const int hl = (T & 31) >> 1;
    const int ihalf = T & 1;
    const int i0 = (mt >> 6)*16 + ihalf*8;
    const int h  = (mt & 63)*16 + hl;
    const size_t po = ((size_t)mt << 8) + (hl << 4) + ihalf*8;
    float s[8] = {};
    #pragma unroll
    for (int sp=0; sp<SPLIT; ++sp){
        f16x8 p = __builtin_nontemporal_load((const f16x8*)&part[(size_t)sp*1048576 + po]);
        #pragma unroll
        for (int e=0;e<8;++e) s[e] += (float)p[e];
    }
    const float SCALE = 3.0517578125e-07f;  // 0.01 / 32768
    #pragma unroll
    for (int e=0;e<8;++e){
        const size_t o = (size_t)(i0+e)*HH + h;
        float r = fminf(1.f, fmaxf(-1.f, fmaf(SCALE, s[e], W[o])));
        __builtin_nontemporal_store(r, &outW[o]);
    }
}

extern "C" void kernel_launch(void* const* d_in, const int* in_sizes, int n_in,
                              void* d_out, int out_size, void* d_ws, size_t ws_size,
                              hipStream_t stream){
    (void)in_sizes; (void)n_in; (void)out_size; (void)ws_size;
    const float* x = (const float*)d_in[0];
    const float* W = (const float*)d_in[1];
    float* hidden = (float*)d_out;
    float* outW   = hidden + (size_t)BB*HH;
    char* ws = (char*)d_ws;
    // ws: xf f16 @0 (64MB) | xt8 fp8 @64M (32MB) | ht8 fp8 @96M (32MB) | wt f16 @128M (2MB)
    //     part f16 [16][I][H] (micro) @0 (32MB, overlaps dead xf)
    f16*           xf   = (f16*)(ws);
    unsigned char* xt8  = (unsigned char*)(ws + 67108864ull);
    unsigned char* ht8  = (unsigned char*)(ws + 100663296ull);
    f16*           wt   = (f16*)(ws + 134217728ull);
    f16*           part = (f16*)(ws);

    k_prep2<<<dim3(528, 16), 256, 0, stream>>>(x, xf, xt8, W, wt);
    k_gemm1<<<dim3((BB/256)*(HH/256)), 512, 0, stream>>>(xf, wt, hidden, ht8);
    k_gemm2<<<dim3(16*SPLIT), 512, 0, stream>>>(xt8, ht8, part);
    k_final<<<dim3((II*HH)/(256*8)), 256, 0, stream>>>(part, W, outW);
}

// Round 15
// 192.649 us; speedup vs baseline: 1.1704x; 1.0131x over previous
//
#include <hip/hip_runtime.h>
#include <hip/hip_fp8.h>
#include <cstdint>

#define BB 32768
#define II 1024
#define HH 1024
#define SPLIT 16
#define KCH (BB/SPLIT)      // 2048
#define NT1 (II/64)         // 16 K-tiles (gemm1)
#define NT2 (KCH/64)        // 32 K-tiles per split (gemm2)

typedef _Float16 f16;
typedef _Float16 f16x4 __attribute__((ext_vector_type(4)));
typedef _Float16 f16x8 __attribute__((ext_vector_type(8)));
typedef float f32x4 __attribute__((ext_vector_type(4)));

typedef const __attribute__((address_space(1))) void gvoid_t;
typedef __attribute__((address_space(3))) void lvoid_t;

__device__ __forceinline__ void gload16(const void* g, void* l){
    __builtin_amdgcn_global_load_lds((gvoid_t*)g, (lvoid_t*)l, 16, 0, 0);
}

__device__ __forceinline__ float tanh_fast(float s){
    float a = fabsf(s);
    float e = __expf(-2.0f * a);
    float t = __fdividef(1.0f - e, 1.0f + e);
    return s < 0.0f ? -t : t;
}

__device__ __forceinline__ unsigned char f2fp8(float v){
    __hip_fp8_e4m3 q(v);
    return (unsigned char)q.__x;
}

// Fused prep: blocks [0,512): x [B][I] -> xf f16 + xt8 fp8 [I][B]
//             blocks [512,528): W [I][H] -> wt f16 [H][I]
__global__ __launch_bounds__(256) void k_prep2(const float* __restrict__ x,
                                               f16* __restrict__ xf,
                                               unsigned char* __restrict__ xt8,
                                               const float* __restrict__ W,
                                               f16* __restrict__ wt){
    __shared__ float lt[64*67];
    const int t = threadIdx.x;
    const int bx = (int)blockIdx.x;
    const bool isX = (bx < 512);
    const float* in = isX ? x : W;
    const int C = isX ? II : HH, R = isX ? BB : II;
    const int r0 = (isX ? bx : bx-512)*64;
    const int c0 = blockIdx.y*64;
    #pragma unroll
    for (int p=0; p<4; ++p){
        int r = p*16 + (t>>4);
        int c = (t&15)*4;
        f32x4 v = __builtin_nontemporal_load((const f32x4*)&in[(size_t)(r0+r)*C + c0 + c]);
        if (isX){
            f16x4 hv = {(f16)v[0],(f16)v[1],(f16)v[2],(f16)v[3]};
            *(f16x4*)&xf[(size_t)(r0+r)*C + c0 + c] = hv;
        }
        lt[r*67 + c+0] = v[0];
        lt[r*67 + c+1] = v[1];
        lt[r*67 + c+2] = v[2];
        lt[r*67 + c+3] = v[3];
    }
    __syncthreads();
    const int c = t>>2, rb = (t&3)*16;
    if (isX){
        union { unsigned char cb[16]; f32x4 v4; } u;
        #pragma unroll
        for (int e=0; e<16; ++e) u.cb[e] = f2fp8(lt[(rb+e)*67 + c]);
        *(f32x4*)&xt8[(size_t)(c0+c)*R + r0 + rb] = u.v4;
    } else {
        f16x8 a, b;
        #pragma unroll
        for (int e=0; e<8; ++e) a[e] = (f16)lt[(rb+e)*67 + c];
        #pragma unroll
        for (int e=0; e<8; ++e) b[e] = (f16)lt[(rb+8+e)*67 + c];
        f16* o = &wt[(size_t)(c0+c)*R + r0 + rb];
        *(f16x8*)o = a;
        *(f16x8*)(o+8) = b;
    }
}

// ================= GEMM1 (f16, 8-phase, peeled last iteration) =================
__device__ __forceinline__ void stage_half(const f16* __restrict__ panel, int ld,
                                           int row0, int kcol0, char* lds_half,
                                           int wid, int lane){
    #pragma unroll
    for (int r=0;r<2;++r){
        int o = r*8192 + wid*1024 + lane*16;
        int rr = o>>7;
        int c0 = (o&127) ^ ((rr&7)<<4);
        gload16(panel + (size_t)(row0 + rr)*ld + kcol0 + (c0>>1), lds_half + r*8192 + wid*1024);
    }
}

#define RD_A(BUFA, mh) { \
    _Pragma("unroll") for (int m_=0;m_<4;++m_){ \
        af[m_][0] = *(const f16x8*)((BUFA) + rowA + (mh)*8192 + m_*2048 + ksw0); \
        af[m_][1] = *(const f16x8*)((BUFA) + rowA + (mh)*8192 + m_*2048 + ksw1); }}

#define RD_B(BUFB, nh) { \
    _Pragma("unroll") for (int n_=0;n_<2;++n_){ \
        bf[(nh)*2+n_][0] = *(const f16x8*)((BUFB) + rowB + (nh)*4096 + n_*2048 + ksw0); \
        bf[(nh)*2+n_][1] = *(const f16x8*)((BUFB) + rowB + (nh)*4096 + n_*2048 + ksw1); }}

#define MFMA_Q(mh,nh) { \
    __builtin_amdgcn_s_setprio(1); \
    _Pragma("unroll") for (int m_=0;m_<4;++m_){ \
      _Pragma("unroll") for (int n_=0;n_<2;++n_){ \
        _Pragma("unroll") for (int ks_=0;ks_<2;++ks_){ \
          acc[(mh)*4+m_][(nh)*2+n_] = __builtin_amdgcn_mfma_f32_16x16x32_f16( \
              af[m_][ks_], bf[(nh)*2+n_][ks_], acc[(mh)*4+m_][(nh)*2+n_], 0,0,0); }}} \
    __builtin_amdgcn_s_setprio(0); }

#define PH_SYNC1 { __builtin_amdgcn_s_barrier(); \
    asm volatile("s_waitcnt lgkmcnt(0)" ::: "memory"); \
    __builtin_amdgcn_sched_barrier(0); }
#define PH_SYNC2 { __builtin_amdgcn_s_barrier(); }
#define LGKM8 { asm volatile("s_waitcnt lgkmcnt(8)" ::: "memory"); }
#define LGKM0SB { asm volatile("s_waitcnt lgkmcnt(0)" ::: "memory"); \
    __builtin_amdgcn_sched_barrier(0); }

// per-quadrant fused epilogue: tanh + ht8 micro-tile u32 + hidden f32 scatter
#define EPI_Q(mh,nh) { \
    _Pragma("unroll") for (int m_=0;m_<4;++m_){ \
      const int b_ = b_base + ((mh)*4+m_)*16; \
      _Pragma("unroll") for (int n_=0;n_<2;++n_){ \
        const int h_ = h_base + ((nh)*2+n_)*16; \
        float t0 = tanh_fast(acc[(mh)*4+m_][(nh)*2+n_][0]); \
        float t1 = tanh_fast(acc[(mh)*4+m_][(nh)*2+n_][1]); \
        float t2 = tanh_fast(acc[(mh)*4+m_][(nh)*2+n_][2]); \
        float t3 = tanh_fast(acc[(mh)*4+m_][(nh)*2+n_][3]); \
        union { unsigned char cb[4]; unsigned int u; } p_; \
        p_.cb[0]=f2fp8(t0); p_.cb[1]=f2fp8(t1); p_.cb[2]=f2fp8(t2); p_.cb[3]=f2fp8(t3); \
        *(unsigned int*)&ht8[(((size_t)(h_>>4)*(BB>>4) + (b_>>4))<<8) + ((h_&15)<<4) + (b_&15)] = p_.u; \
        hidden[(size_t)(b_+0)*HH + h_] = t0; \
        hidden[(size_t)(b_+1)*HH + h_] = t1; \
        hidden[(size_t)(b_+2)*HH + h_] = t2; \
        hidden[(size_t)(b_+3)*HH + h_] = t3; \
    }}}

// GEMM1: hidden[b][h]=tanh(xf·wt); ht8 = fp8(tanh) micro-tiled [h>>4][b>>4][h&15][b&15].
__global__ __launch_bounds__(512,2) void k_gemm1(const f16* __restrict__ xf,
                                                 const f16* __restrict__ wt,
                                                 float* __restrict__ hidden,
                                                 unsigned char* __restrict__ ht8){
    __shared__ char sm[131072];
    const int bid = (int)blockIdx.x;
    const int swz = (bid & 7)*64 + (bid >> 3);
    const int btile = swz >> 2, htile = swz & 3;
    const int arow0 = btile*256, brow0 = htile*256;

    const int t = threadIdx.x, lane = t & 63, wid = t >> 6;
    const int wr = wid >> 2, wc = wid & 3;
    const int fr = lane & 15, kg = lane >> 4;
    char* const A0 = sm;
    char* const B0 = sm + 32768;
    char* const A1 = sm + 65536;
    char* const B1 = sm + 98304;
    const int rowA = wr*16384 + fr*128;
    const int rowB = (wc>>1)*16384 + (wc&1)*8192 + fr*128;
    const int ksw0 = ((kg    ) ^ (fr & 7)) << 4;
    const int ksw1 = ((kg + 4) ^ (fr & 7)) << 4;
    const int b_base = btile*256 + wr*128 + kg*4;
    const int h_base = htile*256 + wc*64 + fr;

    f32x4 acc[8][4] = {};
    f16x8 af[4][2], bf[4][2];

    // prologue: K0 -> buf0 (4 half-tiles), K1 -> B1 half0, A1 half0
    stage_half(xf, II, arow0 +   0,  0, A0,         wid, lane);
    stage_half(xf, II, arow0 + 128,  0, A0 + 16384, wid, lane);
    stage_half(wt, II, brow0 +   0,  0, B0,         wid, lane);
    stage_half(wt, II, brow0 + 128,  0, B0 + 16384, wid, lane);
    stage_half(wt, II, brow0 +   0, 64, B1,         wid, lane);
    stage_half(xf, II, arow0 +   0, 64, A1,         wid, lane);
    asm volatile("s_waitcnt vmcnt(4)" ::: "memory");
    __builtin_amdgcn_s_barrier();

    const int ni = NT1 >> 1;     // 8
    for (int it = 0; it < ni-1; ++it){       // main: K-tiles 0..13, stages 0..15 exactly once
        const int k1 = (2*it + 1) * 64;
        const int k2 = (2*it + 2) * 64;
        const int k3 = (2*it + 3) * 64;
        RD_A(A0, 0); RD_B(B0, 0);
        stage_half(xf, II, arow0 + 128, k1, A1 + 16384, wid, lane);
        LGKM8; PH_SYNC1; MFMA_Q(0,0); PH_SYNC2;
        RD_B(B0, 1);
        stage_half(wt, II, brow0 + 128, k1, B1 + 16384, wid, lane);
        PH_SYNC1; MFMA_Q(0,1); PH_SYNC2;
        RD_A(A0, 1);
        stage_half(wt, II, brow0 +   0, k2, B0, wid, lane);
        PH_SYNC1; MFMA_Q(1,0); PH_SYNC2;
        stage_half(xf, II, arow0 +   0, k2, A0, wid, lane);
        PH_SYNC1; MFMA_Q(1,1);
        asm volatile("s_waitcnt vmcnt(4)" ::: "memory");
        __builtin_amdgcn_s_barrier();
        RD_A(A1, 0); RD_B(B1, 0);
        stage_half(xf, II, arow0 + 128, k2, A0 + 16384, wid, lane);
        LGKM8; PH_SYNC1; MFMA_Q(0,0); PH_SYNC2;
        RD_B(B1, 1);
        stage_half(wt, II, brow0 + 128, k2, B0 + 16384, wid, lane);
        PH_SYNC1; MFMA_Q(0,1); PH_SYNC2;
        RD_A(A1, 1);
        stage_half(wt, II, brow0 +   0, k3, B1, wid, lane);
        PH_SYNC1; MFMA_Q(1,0); PH_SYNC2;
        stage_half(xf, II, arow0 +   0, k3, A1, wid, lane);
        PH_SYNC1; MFMA_Q(1,1);
        asm volatile("s_waitcnt vmcnt(4)" ::: "memory");
        __builtin_amdgcn_s_barrier();
    }

    // peeled tail: K-tiles 14 (buf0) and 15 (buf1); completes tile-15 halves,
    // then barrier-free finish with fused per-quadrant epilogue.
    {
        const int kL = (NT1-1)*64;           // 960
        RD_A(A0, 0); RD_B(B0, 0);
        stage_half(xf, II, arow0 + 128, kL, A1 + 16384, wid, lane);
        LGKM0SB; MFMA_Q(0,0);
        RD_B(B0, 1);
        stage_half(wt, II, brow0 + 128, kL, B1 + 16384, wid, lane);
        LGKM0SB; MFMA_Q(0,1);
        RD_A(A0, 1);
        LGKM0SB; MFMA_Q(1,0);
        MFMA_Q(1,1);
        asm volatile("s_waitcnt vmcnt(0)" ::: "memory");   // all tile-15 stages issued by this wave done
        __builtin_amdgcn_s_barrier();                      // ...and by all waves
        RD_A(A1, 0); RD_B(B1, 0);
        LGKM0SB; MFMA_Q(0,0); EPI_Q(0,0);
        RD_B(B1, 1);
        LGKM0SB; MFMA_Q(0,1); EPI_Q(0,1);
        RD_A(A1, 1);
        LGKM0SB; MFMA_Q(1,0); EPI_Q(1,0);
        MFMA_Q(1,1); EPI_Q(1,1);
    }
}

// ================= GEMM2 (fp8, unchanged from R14) =================
template<bool MT>
__device__ __forceinline__ void stage_half8(const unsigned char* __restrict__ panel, int ld,
                                            int row0, int kcol0, char* lds_half,
                                            int wid, int lane){
    int o  = wid*1024 + lane*16;
    int rr = o>>6;
    int c  = (o&63) ^ ((rr&6)<<3);
    if constexpr (!MT){
        gload16(panel + (size_t)(row0+rr)*ld + kcol0 + c, lds_half + wid*1024);
    } else {
        int h = row0 + rr;
        int babs = kcol0 + c;
        gload16(panel + (((size_t)(h>>4)*(BB>>4) + (babs>>4))<<8) + ((h&15)<<4) + (babs&15),
                lds_half + wid*1024);
    }
}

#define RD_A8(BUFA, mh) { \
    _Pragma("unroll") for (int m_=0;m_<4;++m_){ \
        afl[m_][0] = *(const long*)((BUFA) + rowA8 + (mh)*4096 + m_*1024 + k80); \
        afl[m_][1] = *(const long*)((BUFA) + rowA8 + (mh)*4096 + m_*1024 + k81); }}

#define RD_B8(BUFB, nh) { \
    _Pragma("unroll") for (int n_=0;n_<2;++n_){ \
        bfl[(nh)*2+n_][0] = *(const long*)((BUFB) + rowB8 + (nh)*2048 + n_*1024 + k80); \
        bfl[(nh)*2+n_][1] = *(const long*)((BUFB) + rowB8 + (nh)*2048 + n_*1024 + k81); }}

#define MFMA_Q8(mh,nh) { \
    __builtin_amdgcn_s_setprio(1); \
    _Pragma("unroll") for (int m_=0;m_<4;++m_){ \
      _Pragma("unroll") for (int n_=0;n_<2;++n_){ \
        _Pragma("unroll") for (int ks_=0;ks_<2;++ks_){ \
          acc[(mh)*4+m_][(nh)*2+n_] = __builtin_amdgcn_mfma_f32_16x16x32_fp8_fp8( \
              afl[m_][ks_], bfl[(nh)*2+n_][ks_], acc[(mh)*4+m_][(nh)*2+n_], 0,0,0); }}} \
    __builtin_amdgcn_s_setprio(0); }

__global__ __launch_bounds__(512,2) void k_gemm2(const unsigned char* __restrict__ xt8,
                                                 const unsigned char* __restrict__ ht8,
                                                 f16* __restrict__ part){
    __shared__ char sm[65536];           // A0 16K | B0 16K | A1 16K | B1 16K
    const int bid = (int)blockIdx.x;
    const int swz = (bid & 7)*32 + (bid >> 3);
    const int split = swz >> 4, tile = swz & 15;
    const int itile = tile & 3, htile = tile >> 2;
    const int arow0 = itile*256, brow0 = htile*256, kbase = split*KCH;

    const int t = threadIdx.x, lane = t & 63, wid = t >> 6;
    const int wr = wid >> 2, wc = wid & 3;
    const int fr = lane & 15, kg = lane >> 4;
    const int mask = NT2 - 1;
    char* const A0 = sm;
    char* const B0 = sm + 16384;
    char* const A1 = sm + 32768;
    char* const B1 = sm + 49152;
    const int rowA8 = wr*8192 + fr*64;
    const int rowB8 = (wc>>1)*8192 + (wc&1)*4096 + fr*64;
    const int s6  = fr & 6;
    const int k80 = ((kg    ) ^ s6) << 3;
    const int k81 = ((kg + 4) ^ s6) << 3;

    f32x4 acc[8][4] = {};
    long afl[4][2], bfl[4][2];

    stage_half8<false>(xt8, BB, arow0 +   0, kbase +  0, A0,        wid, lane);
    stage_half8<false>(xt8, BB, arow0 + 128, kbase +  0, A0 + 8192, wid, lane);
    stage_half8<true >(ht8, BB, brow0 +   0, kbase +  0, B0,        wid, lane);
    stage_half8<true >(ht8, BB, brow0 + 128, kbase +  0, B0 + 8192, wid, lane);
    stage_half8<true >(ht8, BB, brow0 +   0, kbase + 64, B1,        wid, lane);
    stage_half8<false>(xt8, BB, arow0 +   0, kbase + 64, A1,        wid, lane);
    asm volatile("s_waitcnt vmcnt(2)" ::: "memory");
    __builtin_amdgcn_s_barrier();

    const int ni = NT2 >> 1;
    for (int it = 0; it < ni; ++it){
        const int k1 = (2*it + 1) * 64;
        const int k2 = ((2*it + 2) & mask) * 64;
        const int k3 = ((2*it + 3) & mask) * 64;
        RD_A8(A0, 0); RD_B8(B0, 0);
        stage_half8<false>(xt8, BB, arow0 + 128, kbase + k1, A1 + 8192, wid, lane);
        PH_SYNC1; MFMA_Q8(0,0); PH_SYNC2;
        RD_B8(B0, 1);
        stage_half8<true>(ht8, BB, brow0 + 128, kbase + k1, B1 + 8192, wid, lane);
        PH_SYNC1; MFMA_Q8(0,1); PH_SYNC2;
        RD_A8(A0, 1);
        stage_half8<true>(ht8, BB, brow0 +   0, kbase + k2, B0, wid, lane);
        PH_SYNC1; MFMA_Q8(1,0); PH_SYNC2;
        stage_half8<false>(xt8, BB, arow0 +   0, kbase + k2, A0, wid, lane);
        PH_SYNC1; MFMA_Q8(1,1);
        asm volatile("s_waitcnt vmcnt(2)" ::: "memory");
        __builtin_amdgcn_s_barrier();
        RD_A8(A1, 0); RD_B8(B1, 0);
        stage_half8<false>(xt8, BB, arow0 + 128, kbase + k2, A0 + 8192, wid, lane);
        PH_SYNC1; MFMA_Q8(0,0); PH_SYNC2;
        RD_B8(B1, 1);
        stage_half8<true>(ht8, BB, brow0 + 128, kbase + k2, B0 + 8192, wid, lane);
        PH_SYNC1; MFMA_Q8(0,1); PH_SYNC2;
        RD_A8(A1, 1);
        stage_half8<true>(ht8, BB, brow0 +   0, kbase + k3, B1, wid, lane);
        PH_SYNC1; MFMA_Q8(1,0); PH_SYNC2;
        stage_half8<false>(xt8, BB, arow0 +   0, kbase + k3, A1, wid, lane);
        PH_SYNC1; MFMA_Q8(1,1);
        asm volatile("s_waitcnt vmcnt(2)" ::: "memory");
        __builtin_amdgcn_s_barrier();
    }
    asm volatile("s_waitcnt vmcnt(0)" ::: "memory");
    __builtin_amdgcn_s_barrier();

    const size_t pb = (size_t)split*II*HH;
    #pragma unroll
    for (int mf=0; mf<8; ++mf){
        const int i0 = itile*256 + wr*128 + mf*16 + kg*4;
        #pragma unroll
        for (int nf=0; nf<4; ++nf){
            const int h = htile*256 + wc*64 + nf*16 + fr;
            f16x4 pv = {(f16)acc[mf][nf][0],(f16)acc[mf][nf][1],
                        (f16)acc[mf][nf][2],(f16)acc[mf][nf][3]};
            *(f16x4*)&part[pb + (((size_t)(i0>>4)*(HH>>4) + (h>>4))<<8) + ((h&15)<<4) + (i0&15)] = pv;
        }
    }
}

__global__ __launch_bounds__(256) void k_final(const f16* __restrict__ part,
                                               const float* __restrict__ W,
                                               float* __restrict__ outW){
    const int T = (int)blockIdx.x*256 + threadIdx.x;   // 0..131071
    const int mt = T >> 5;
    const int hl = (T & 31) >> 1;
    const int ihalf = T & 1;
    const int i0 = (mt >> 6)*16 + ihalf*8;
    const int h  = (mt & 63)*16 + hl;
    const size_t po = ((size_t)mt << 8) + (hl << 4) + ihalf*8;
    float s[8] = {};
    #pragma unroll
    for (int sp=0; sp<SPLIT; ++sp){
        f16x8 p = __builtin_nontemporal_load((const f16x8*)&part[(size_t)sp*1048576 + po]);
        #pragma unroll
        for (int e=0;e<8;++e) s[e] += (float)p[e];
    }
    const float SCALE = 3.0517578125e-07f;  // 0.01 / 32768
    #pragma unroll
    for (int e=0;e<8;++e){
        const size_t o = (size_t)(i0+e)*HH + h;
        float r = fminf(1.f, fmaxf(-1.f, fmaf(SCALE, s[e], W[o])));
        __builtin_nontemporal_store(r, &outW[o]);
    }
}

extern "C" void kernel_launch(void* const* d_in, const int* in_sizes, int n_in,
                              void* d_out, int out_size, void* d_ws, size_t ws_size,
                              hipStream_t stream){
    (void)in_sizes; (void)n_in; (void)out_size; (void)ws_size;
    const float* x = (const float*)d_in[0];
    const float* W = (const float*)d_in[1];
    float* hidden = (float*)d_out;
    float* outW   = hidden + (size_t)BB*HH;
    char* ws = (char*)d_ws;
    // ws: xf f16 @0 (64MB) | xt8 fp8 @64M (32MB) | ht8 fp8 @96M (32MB) | wt f16 @128M (2MB)
    //     part f16 [16][I][H] (micro) @0 (32MB, overlaps dead xf)
    f16*           xf   = (f16*)(ws);
    unsigned char* xt8  = (unsigned char*)(ws + 67108864ull);
    unsigned char* ht8  = (unsigned char*)(ws + 100663296ull);
    f16*           wt   = (f16*)(ws + 134217728ull);
    f16*           part = (f16*)(ws);

    k_prep2<<<dim3(528, 16), 256, 0, stream>>>(x, xf, xt8, W, wt);
    k_gemm1<<<dim3((BB/256)*(HH/256)), 512, 0, stream>>>(xf, wt, hidden, ht8);
    k_gemm2<<<dim3(16*SPLIT), 512, 0, stream>>>(xt8, ht8, part);
    k_final<<<dim3((II*HH)/(256*8)), 256, 0, stream>>>(part, W, outW);
}